// Round 5
// baseline (1199.086 us; speedup 1.0000x reference)
//
#include <hip/hip_runtime.h>
#include <math.h>

typedef unsigned short u16;
typedef unsigned int u32;
typedef __attribute__((ext_vector_type(8))) short bf16x8;
typedef __attribute__((ext_vector_type(4))) float f32x4;

#define MFMA16(a,b,c) __builtin_amdgcn_mfma_f32_16x16x32_bf16(a,b,c,0,0,0)

typedef __attribute__((address_space(1))) const unsigned int as1_u32;
typedef __attribute__((address_space(3))) unsigned int as3_u32;
__device__ __forceinline__ void gld16(const u16* g, u16* l){
  __builtin_amdgcn_global_load_lds((as1_u32*)g, (as3_u32*)l, 16, 0, 0);
}

__device__ __forceinline__ u16 f2bf(float x){
  union { float f; u32 u; } v; v.f = x;
  u32 u = v.u;
  return (u16)((u + 0x7fffu + ((u>>16)&1u)) >> 16);
}

__device__ __forceinline__ void memfence(){ asm volatile("" ::: "memory"); }

union B8 { bf16x8 v; u32 u[4]; uint4 q; };

// ---------------- K0: fold BN into bf16 weights ----------------
__global__ void k0_prep(const float* wm, const float* bias, const float* gamma,
                        const float* beta, const float* mean, const float* var,
                        float extra, u16* wdst, float* ddst)
{
  int t = threadIdx.x;
  if (t < 64){
    float a0 = gamma[t] * rsqrtf(var[t] + 1e-5f);
    ddst[t] = (beta[t] + (bias[t] - mean[t]) * a0) * extra;
  }
  for (int i = t; i < 4096; i += 256){
    int o = i >> 6;
    float a0 = gamma[o] * rsqrtf(var[o] + 1e-5f);
    wdst[i] = f2bf(wm[i] * a0 * extra);
  }
}

// ---------------- K1: QKV projection + BN; q,k row-major, v transposed ----------
__global__ __launch_bounds__(256,2)
void k1_qkv(const float* __restrict__ f, const u16* __restrict__ wz,
            const float* __restrict__ dz, u16* __restrict__ q,
            u16* __restrict__ kk_, u16* __restrict__ vt)
{
  int bid = blockIdx.x;
  int b  = bid >> 7;
  int ht = (bid >> 3) & 15;
  int wt = bid & 7;
  int tid = threadIdx.x;
  int wv = tid >> 6, lane = tid & 63;
  int l15 = lane & 15, l4 = lane >> 4;
  int h0 = ht * 32;
  int w0 = wt * 64 + wv * 16;

  bf16x8 wa[3][4][2];
  #pragma unroll
  for (int mt=0; mt<3; mt++)
    #pragma unroll
    for (int m=0;m<4;m++)
      #pragma unroll
      for (int ks=0;ks<2;ks++){
        B8 t; t.q = *(const uint4*)(wz + mt*4096 + (m*16+l15)*64 + ks*32 + l4*8);
        wa[mt][m][ks] = t.v;
      }
  f32x4 dv[3][4];
  #pragma unroll
  for (int mt=0;mt<3;mt++)
    #pragma unroll
    for (int m=0;m<4;m++)
      dv[mt][m] = *(const f32x4*)(dz + mt*64 + m*16 + l4*4);

  __shared__ u16 vstage[4][8704];
  u16* vs = vstage[wv];

  B8 bf[2];
  #pragma unroll
  for (int ks=0;ks<2;ks++)
    #pragma unroll
    for (int jj=0;jj<4;jj++){
      int c0 = ks*32 + l4*8 + jj*2;
      size_t i0 = ((size_t)(b*64 + c0)*512 + h0)*512 + w0 + l15;
      bf[ks].u[jj] = (u32)f2bf(f[i0]) | ((u32)f2bf(f[i0 + 262144]) << 16);
    }

  for (int hh=0; hh<32; hh++){
    int h = h0 + hh;
    B8 bfn[2];
    if (hh < 31){
      #pragma unroll
      for (int ks=0;ks<2;ks++)
        #pragma unroll
        for (int jj=0;jj<4;jj++){
          int c0 = ks*32 + l4*8 + jj*2;
          size_t i0 = ((size_t)(b*64 + c0)*512 + h + 1)*512 + w0 + l15;
          bfn[ks].u[jj] = (u32)f2bf(f[i0]) | ((u32)f2bf(f[i0 + 262144]) << 16);
        }
    }
    #pragma unroll
    for (int mt=0; mt<3; mt++){
      f32x4 acc[4];
      #pragma unroll
      for (int m=0;m<4;m++) acc[m] = (f32x4){0.f,0.f,0.f,0.f};
      #pragma unroll
      for (int m=0;m<4;m++)
        #pragma unroll
        for (int ks=0;ks<2;ks++)
          acc[m] = MFMA16(wa[mt][m][ks], bf[ks].v, acc[m]);
      #pragma unroll
      for (int m=0;m<4;m++)
        #pragma unroll
        for (int r=0;r<4;r++){
          float val = acc[m][r] + dv[mt][m][r];
          u16 bv = f2bf(val);
          int o = m*16 + l4*4 + r;
          if (mt==0)      q  [((size_t)(b*64+o)*512 + h)*512 + w0 + l15] = bv;
          else if (mt==1) kk_[((size_t)(b*64+o)*512 + h)*512 + w0 + l15] = bv;
          else            vs[o*136 + l15*8 + (hh&7)] = bv;
        }
    }
    bf[0] = bfn[0]; bf[1] = bfn[1];
    if ((hh&7)==7){
      __syncthreads();
      int hb = h - 7;
      #pragma unroll
      for (int r=0;r<16;r++){
        int o = r*4 + l4;
        uint4 d = *(const uint4*)(vs + o*136 + l15*8);
        *(uint4*)(vt + ((size_t)(b*64+o)*512 + (w0+l15))*512 + hb) = d;
      }
      __syncthreads();
    }
  }
}

// ---------------- K23 v4: flash attention, 4-wave blocks, 2 blocks/CU ----------
// grid 2048 (head x 8 q-tiles of 64 rows), 256 thr. Pair-processing: 2 K-tiles
// of 16 g per iteration (32 g), pair-level softmax, PV per pair (K-dim 32).
// LDS 69KB: K pair dbuf-by-halves 32KB + V 32KB + P 5KB -> 2 blocks/CU.
// Swizzle: chunk c ^= (row&3): gld16 sources stay coalesced (row wave-uniform),
// ds_read addrs = per-lane base + imm (row&3 == l15&3), 2-way conflicts (free).
__global__ __launch_bounds__(256,2)
void k23_attn(const u16* __restrict__ q, const u16* __restrict__ kten,
              const u16* __restrict__ vt, u16* __restrict__ o2)
{
  int phys = blockIdx.x;
  int x = phys & 7, j = phys >> 3;        // XCD-swizzle: 8 x 256
  int head = x*32 + (j >> 3);
  int q0 = (j & 7) * 64;
  int b = head >> 6, c = head & 63;

  int tid = threadIdx.x;
  int wv = tid >> 6, lane = tid & 63;
  int l15 = lane & 15, l4 = lane >> 4;

  const u16* qh = q    + (size_t)head*262144;
  const u16* kh = kten + (size_t)head*262144;
  const u16* vh = vt   + (size_t)head*262144;   // vh[w*512+g] = V[g][w]

  __shared__ u16 KB[16384];   // [g 0..31][c 0..63] 16B chunks; LDS[g][c]=Gk[g][c^(g&3)]
  __shared__ u16 VB[16384];   // [w 0..511][c 0..3] 16B chunks; LDS[w][c]=Gv[w][c^(w&3)]
  __shared__ u16 Pt[2560];    // [qq 0..63][40] (stride 80B: odd x16 -> conflict-free)

  auto stageK = [&](int pr){
    const u16* src = kh + (size_t)pr*16384;
    #pragma unroll
    for (int i=0;i<8;i++){
      int slot = i*256 + tid;             // g = slot>>6 (wave-uniform), cc = slot&63
      int g = slot >> 6, cc = slot & 63;
      gld16(src + (size_t)g*512 + ((cc ^ (g&3))<<3), &KB[slot*8]);
    }
  };
  auto stageV = [&](int pr){
    const u16* src = vh + pr*32;
    #pragma unroll
    for (int i=0;i<8;i++){
      int slot = i*256 + tid;             // w = slot>>2, cc = slot&3
      int w = slot >> 2, cc = slot & 3;
      gld16(src + (size_t)w*512 + ((cc ^ (w&3))<<3), &VB[slot*8]);
    }
  };

  // prologue: Q->regs (16 vmem), then K(pair0) 8, V(pair0) 8
  uint4 qreg[16];
  {
    const u16* qrow = qh + (size_t)(q0 + wv*16 + l15)*512;
    #pragma unroll
    for (int ks=0;ks<16;ks++) qreg[ks] = *(const uint4*)(qrow + ks*32 + l4*8);
  }
  stageK(0); stageV(0);
  asm volatile("s_waitcnt vmcnt(8)" ::: "memory");   // Q + K landed, V in flight
  __builtin_amdgcn_s_barrier(); memfence();

  f32x4 oacc[32];
  #pragma unroll
  for (int n=0;n<32;n++) oacc[n] = (f32x4){0.f,0.f,0.f,0.f};
  float m_run[4] = {-1e30f,-1e30f,-1e30f,-1e30f};
  float l_run[4] = {0.f,0.f,0.f,0.f};

  // per-lane LDS element bases (all read offsets are compile-time immediates)
  const int kbase = l15*512 + ((l4 ^ (l15&3))<<3);   // + s*8192 + ks*32
  const int vbase = l15*32  + ((l4 ^ (l15&3))<<3);   // + n*512
  const int pbase = (wv*16 + l15)*40;                // + l4*8

  for (int p=0; p<16; ++p){
    // ===== S phase: 32 g via two 16-g tiles, 4 MFMA chains =====
    f32x4 s00={0.f,0.f,0.f,0.f}, s01={0.f,0.f,0.f,0.f};
    f32x4 s10={0.f,0.f,0.f,0.f}, s11={0.f,0.f,0.f,0.f};
    __builtin_amdgcn_s_setprio(1);
    #pragma unroll
    for (int ks=0; ks<16; ks+=2){
      B8 b0; b0.q = *(const uint4*)(KB + kbase + ks*32);
      B8 b1; b1.q = *(const uint4*)(KB + kbase + (ks+1)*32);
      B8 a0; a0.q = qreg[ks];
      B8 a1; a1.q = qreg[ks+1];
      s00 = MFMA16(a0.v, b0.v, s00);
      s01 = MFMA16(a1.v, b1.v, s01);
    }
    #pragma unroll
    for (int ks=0; ks<16; ks+=2){
      B8 b0; b0.q = *(const uint4*)(KB + 8192 + kbase + ks*32);
      B8 b1; b1.q = *(const uint4*)(KB + 8192 + kbase + (ks+1)*32);
      B8 a0; a0.q = qreg[ks];
      B8 a1; a1.q = qreg[ks+1];
      s10 = MFMA16(a0.v, b0.v, s10);
      s11 = MFMA16(a1.v, b1.v, s11);
    }
    __builtin_amdgcn_s_setprio(0);
    f32x4 sacc0 = s00 + s01;
    f32x4 sacc1 = s10 + s11;

    // ===== pair softmax (rows = wv*16 + l4*4 + r), defer-max THR=4 =====
    float pm[4], fc[4];
    bool need = false;
    #pragma unroll
    for (int r=0;r<4;r++){
      float pv = fmaxf(sacc0[r], sacc1[r]);
      #pragma unroll
      for (int d=1; d<16; d<<=1) pv = fmaxf(pv, __shfl_xor(pv, d, 64));
      pm[r] = pv;
      need = need || (pv > m_run[r] + 4.0f);
    }
    if (__any(need ? 1 : 0)){
      #pragma unroll
      for (int r=0;r<4;r++){
        float mn = fmaxf(m_run[r], pm[r]);
        fc[r] = exp2f(m_run[r] - mn);
        m_run[r] = mn;
      }
      #pragma unroll
      for (int n=0;n<32;n++)
        #pragma unroll
        for (int r=0;r<4;r++) oacc[n][r] *= fc[r];
    } else {
      fc[0]=fc[1]=fc[2]=fc[3]=1.0f;
    }
    #pragma unroll
    for (int r=0;r<4;r++){
      float e0 = exp2f(sacc0[r] - m_run[r]);
      float e1 = exp2f(sacc1[r] - m_run[r]);
      float s = e0 + e1;
      #pragma unroll
      for (int d=1; d<16; d<<=1) s += __shfl_xor(s, d, 64);
      l_run[r] = l_run[r]*fc[r] + s;
      sacc0[r] = e0; sacc1[r] = e1;
    }
    // P write (own rows; consumed by same wave after barrier)
    #pragma unroll
    for (int r=0;r<4;r++){
      int row = wv*16 + l4*4 + r;
      Pt[row*40 + l15]      = f2bf(sacc0[r]);
      Pt[row*40 + 16 + l15] = f2bf(sacc1[r]);
    }

    asm volatile("s_waitcnt lgkmcnt(0)" ::: "memory");  // my K-reads + P-writes done
    asm volatile("s_waitcnt vmcnt(0)" ::: "memory");    // my V(p) DMAs landed
    __builtin_amdgcn_s_barrier(); memfence();           // K bufs free, VB readable

    if (p < 15) stageK(p+1);                            // refill K under PV

    // ===== PV phase: O[16q x 512w] += P(16q x 32g) * V(32g x 512w) =====
    B8 pa; pa.q = *(const uint4*)(Pt + pbase + l4*8);
    __builtin_amdgcn_s_setprio(1);
    #pragma unroll
    for (int n=0;n<32;n++){
      B8 bb; bb.q = *(const uint4*)(VB + vbase + n*512);
      oacc[n] = MFMA16(pa.v, bb.v, oacc[n]);
    }
    __builtin_amdgcn_s_setprio(0);

    asm volatile("s_waitcnt lgkmcnt(0)" ::: "memory");  // my P/V reads done
    __builtin_amdgcn_s_barrier(); memfence();           // VB free
    if (p < 15){
      stageV(p+1);
      asm volatile("s_waitcnt vmcnt(8)" ::: "memory");  // K(p+1) landed (V in flight)
    }
    __builtin_amdgcn_s_barrier(); memfence();           // K(p+1) visible to all
  }

  // ===== epilogue: write O in interleaved-pair layout into o2 =====
  u16* dst = o2 + (size_t)b*33554432 + 16777216
                + (size_t)(c>>1)*524288 + (c&1);
  #pragma unroll
  for (int r=0;r<4;r++){
    float inv = 1.0f / l_run[r];
    int qq = q0 + wv*16 + l4*4 + r;
    #pragma unroll
    for (int n=0;n<32;n++){
      int w = n*16 + l15;
      dst[(size_t)qq*1024 + w*2] = f2bf(oacc[n][r]*inv);
    }
  }
}

// ---------------- K4 v2: out conv + BN + residual ----------------
__global__ __launch_bounds__(512,2)
void k4_out(const u16* __restrict__ o2, const u16* __restrict__ wz,
            const float* __restrict__ dz, const float* __restrict__ f,
            float* __restrict__ out)
{
  int bid = blockIdx.x;
  int b = bid >> 9;
  int h = bid & 511;
  int tid = threadIdx.x, wv = tid>>6, lane = tid&63;
  int l15 = lane&15, l4 = lane>>4;

  __shared__ u16 Ost[32*1032];

  const u16* src0 = o2 + (size_t)b*33554432 + 16777216 + (size_t)h*1024;
  #pragma unroll
  for (int jj=0;jj<4;jj++){
    int row = jj*8 + wv;
    const u16* srow = src0 + (size_t)row*524288;
    #pragma unroll
    for (int hf=0;hf<2;hf++){
      gld16(srow + hf*512 + lane*8, &Ost[row*1032 + hf*512 + lane*8]);
    }
  }

  bf16x8 wa[4][2];
  #pragma unroll
  for (int m=0;m<4;m++)
    #pragma unroll
    for (int ks=0;ks<2;ks++){
      B8 t; t.q = *(const uint4*)(wz + 3*4096 + (m*16+l15)*64 + ks*32 + l4*8);
      wa[m][ks] = t.v;
    }
  f32x4 dvv[4];
  #pragma unroll
  for (int m=0;m<4;m++) dvv[m] = *(const f32x4*)(dz + 3*64 + m*16 + l4*4);

  asm volatile("s_waitcnt vmcnt(0)" ::: "memory");
  __syncthreads();

  f32x4 acc[4][4];
  #pragma unroll
  for (int m=0;m<4;m++)
    #pragma unroll
    for (int n=0;n<4;n++) acc[m][n] = (f32x4){0.f,0.f,0.f,0.f};

  const u16* obase = Ost + l4*4128 + wv*128 + l15*2;
  #pragma unroll
  for (int ks=0;ks<2;ks++){
    #pragma unroll
    for (int n=0;n<4;n++){
      B8 bb;
      #pragma unroll
      for (int jj=0;jj<4;jj++)
        bb.u[jj] = *(const u32*)(obase + ks*16512 + jj*1032 + n*32);
      #pragma unroll
      for (int m=0;m<4;m++)
        acc[m][n] = MFMA16(wa[m][ks], bb.v, acc[m][n]);
    }
  }
  #pragma unroll
  for (int m=0;m<4;m++)
    #pragma unroll
    for (int n=0;n<4;n++)
      #pragma unroll
      for (int r=0;r<4;r++){
        int o = m*16 + l4*4 + r;
        int w = wv*64 + n*16 + l15;
        size_t idx = ((size_t)(b*64+o)*512 + h)*512 + w;
        out[idx] = acc[m][n][r] + dvv[m][r] + f[idx];
      }
}

// ---------------- launch ----------------
extern "C" void kernel_launch(void* const* d_in, const int* in_sizes, int n_in,
                              void* d_out, int out_size, void* d_ws, size_t ws_size,
                              hipStream_t stream) {
  const float* feat = (const float*)d_in[0];
  char* ws = (char*)d_ws;
  u16*   wz   = (u16*)ws;
  float* dz   = (float*)(ws + 32768);
  u16* bufQ = (u16*)(ws + 65536);     // q
  u16* bufK = bufQ + 67108864ull;     // k
  u16* bufV = bufK + 67108864ull;     // vT
  u16* o2   = (u16*)d_out;            // O pair-layout scratch in d_out's per-b upper 32MB

  float extraK = 1.4426950408889634f / sqrtf(512.0f);  // fold 1/sqrt(W)*log2(e) into K
  for (int m=0; m<4; m++){
    int base = 1 + m*6;
    float extra = (m==1) ? extraK : 1.0f;
    k0_prep<<<dim3(1), dim3(256), 0, stream>>>(
        (const float*)d_in[base+0], (const float*)d_in[base+1],
        (const float*)d_in[base+2], (const float*)d_in[base+3],
        (const float*)d_in[base+4], (const float*)d_in[base+5],
        extra, wz + m*4096, dz + m*64);
  }
  k1_qkv   <<<dim3(512),  dim3(256), 0, stream>>>(feat, wz, dz, bufQ, bufK, bufV);
  k23_attn <<<dim3(2048), dim3(256), 0, stream>>>(bufQ, bufK, bufV, o2);
  k4_out   <<<dim3(2048), dim3(512), 0, stream>>>(o2, wz, dz, feat, (float*)d_out);
}

// Round 6
// 854.911 us; speedup vs baseline: 1.4026x; 1.4026x over previous
//
#include <hip/hip_runtime.h>
#include <math.h>

typedef unsigned short u16;
typedef unsigned int u32;
typedef __attribute__((ext_vector_type(8))) short bf16x8;
typedef __attribute__((ext_vector_type(4))) float f32x4;

#define MFMA16(a,b,c) __builtin_amdgcn_mfma_f32_16x16x32_bf16(a,b,c,0,0,0)

typedef __attribute__((address_space(1))) const unsigned int as1_u32;
typedef __attribute__((address_space(3))) unsigned int as3_u32;
__device__ __forceinline__ void gld16(const u16* g, u16* l){
  __builtin_amdgcn_global_load_lds((as1_u32*)g, (as3_u32*)l, 16, 0, 0);
}

__device__ __forceinline__ u16 f2bf(float x){
  union { float f; u32 u; } v; v.f = x;
  u32 u = v.u;
  return (u16)((u + 0x7fffu + ((u>>16)&1u)) >> 16);
}

__device__ __forceinline__ void memfence(){ asm volatile("" ::: "memory"); }

union B8 { bf16x8 v; u32 u[4]; uint4 q; };

// ---------------- K0: fold BN into bf16 weights ----------------
__global__ void k0_prep(const float* wm, const float* bias, const float* gamma,
                        const float* beta, const float* mean, const float* var,
                        float extra, u16* wdst, float* ddst)
{
  int t = threadIdx.x;
  if (t < 64){
    float a0 = gamma[t] * rsqrtf(var[t] + 1e-5f);
    ddst[t] = (beta[t] + (bias[t] - mean[t]) * a0) * extra;
  }
  for (int i = t; i < 4096; i += 256){
    int o = i >> 6;
    float a0 = gamma[o] * rsqrtf(var[o] + 1e-5f);
    wdst[i] = f2bf(wm[i] * a0 * extra);
  }
}

// ---------------- K1: QKV projection + BN; q,k row-major, v transposed ----------
__global__ __launch_bounds__(256,2)
void k1_qkv(const float* __restrict__ f, const u16* __restrict__ wz,
            const float* __restrict__ dz, u16* __restrict__ q,
            u16* __restrict__ kk_, u16* __restrict__ vt)
{
  int bid = blockIdx.x;
  int b  = bid >> 7;
  int ht = (bid >> 3) & 15;
  int wt = bid & 7;
  int tid = threadIdx.x;
  int wv = tid >> 6, lane = tid & 63;
  int l15 = lane & 15, l4 = lane >> 4;
  int h0 = ht * 32;
  int w0 = wt * 64 + wv * 16;

  bf16x8 wa[3][4][2];
  #pragma unroll
  for (int mt=0; mt<3; mt++)
    #pragma unroll
    for (int m=0;m<4;m++)
      #pragma unroll
      for (int ks=0;ks<2;ks++){
        B8 t; t.q = *(const uint4*)(wz + mt*4096 + (m*16+l15)*64 + ks*32 + l4*8);
        wa[mt][m][ks] = t.v;
      }
  f32x4 dv[3][4];
  #pragma unroll
  for (int mt=0;mt<3;mt++)
    #pragma unroll
    for (int m=0;m<4;m++)
      dv[mt][m] = *(const f32x4*)(dz + mt*64 + m*16 + l4*4);

  __shared__ u16 vstage[4][8704];
  u16* vs = vstage[wv];

  B8 bf[2];
  #pragma unroll
  for (int ks=0;ks<2;ks++)
    #pragma unroll
    for (int jj=0;jj<4;jj++){
      int c0 = ks*32 + l4*8 + jj*2;
      size_t i0 = ((size_t)(b*64 + c0)*512 + h0)*512 + w0 + l15;
      bf[ks].u[jj] = (u32)f2bf(f[i0]) | ((u32)f2bf(f[i0 + 262144]) << 16);
    }

  for (int hh=0; hh<32; hh++){
    int h = h0 + hh;
    B8 bfn[2];
    if (hh < 31){
      #pragma unroll
      for (int ks=0;ks<2;ks++)
        #pragma unroll
        for (int jj=0;jj<4;jj++){
          int c0 = ks*32 + l4*8 + jj*2;
          size_t i0 = ((size_t)(b*64 + c0)*512 + h + 1)*512 + w0 + l15;
          bfn[ks].u[jj] = (u32)f2bf(f[i0]) | ((u32)f2bf(f[i0 + 262144]) << 16);
        }
    }
    #pragma unroll
    for (int mt=0; mt<3; mt++){
      f32x4 acc[4];
      #pragma unroll
      for (int m=0;m<4;m++) acc[m] = (f32x4){0.f,0.f,0.f,0.f};
      #pragma unroll
      for (int m=0;m<4;m++)
        #pragma unroll
        for (int ks=0;ks<2;ks++)
          acc[m] = MFMA16(wa[mt][m][ks], bf[ks].v, acc[m]);
      #pragma unroll
      for (int m=0;m<4;m++)
        #pragma unroll
        for (int r=0;r<4;r++){
          float val = acc[m][r] + dv[mt][m][r];
          u16 bv = f2bf(val);
          int o = m*16 + l4*4 + r;
          if (mt==0)      q  [((size_t)(b*64+o)*512 + h)*512 + w0 + l15] = bv;
          else if (mt==1) kk_[((size_t)(b*64+o)*512 + h)*512 + w0 + l15] = bv;
          else            vs[o*136 + l15*8 + (hh&7)] = bv;
        }
    }
    bf[0] = bfn[0]; bf[1] = bfn[1];
    if ((hh&7)==7){
      __syncthreads();
      int hb = h - 7;
      #pragma unroll
      for (int r=0;r<16;r++){
        int o = r*4 + l4;
        uint4 d = *(const uint4*)(vs + o*136 + l15*8);
        *(uint4*)(vt + ((size_t)(b*64+o)*512 + (w0+l15))*512 + hb) = d;
      }
      __syncthreads();
    }
  }
}

// ---------------- K23 v5: flash attention (R3 skeleton + coalesced swizzle,
// split-phase staging, wave-private P/rescale) ----------------
// grid 1024, 512 thr (8 waves). QBLK=128 (wave owns 16 q-rows end-to-end),
// KVBLK=32, 16 tiles. K/V dbuf via gld16; chunk swizzle c^=(row&3):
// coalesced sources + immediate-offset reads. 2 barriers/iter.
__global__ __launch_bounds__(512,2)
void k23_attn(const u16* __restrict__ q, const u16* __restrict__ kten,
              const u16* __restrict__ vt, u16* __restrict__ o2)
{
  int phys = blockIdx.x;
  int x = phys & 7, j = phys >> 3;
  int qt = j & 3, hh = j >> 2;
  int head = x*32 + hh;
  int q0 = qt*128;
  int b = head >> 6, c = head & 63;

  int tid = threadIdx.x;
  int wv = tid >> 6, lane = tid & 63;
  int l15 = lane & 15, l4 = lane >> 4;

  const u16* qh = q    + (size_t)head*262144;
  const u16* kh = kten + (size_t)head*262144;
  const u16* vh = vt   + (size_t)head*262144;   // vh[w*512+g] = V[g][w]

  __shared__ u16 KB[2][16384];  // [g 0..31][chunk 0..63]; slot c holds global c^(g&3)
  __shared__ u16 VB[2][16384];  // [w 0..511][chunk 0..3]; slot c holds global c^(w&3)
  __shared__ u16 Pt[5120];      // [q 0..127][40] wave-private rows

  auto stageK = [&](int jt, int buf){
    const u16* src = kh + (size_t)jt*16384;
    #pragma unroll
    for (int i=0;i<4;i++){
      int slot = i*512 + tid;
      int g = slot >> 6, cc = slot & 63;
      gld16(src + (size_t)g*512 + ((cc ^ (g&3))<<3), &KB[buf][slot*8]);
    }
  };
  auto stageV = [&](int jt, int buf){
    const u16* src = vh + jt*32;
    #pragma unroll
    for (int i=0;i<4;i++){
      int slot = i*512 + tid;
      int w = slot >> 2, cc = slot & 3;
      gld16(src + (size_t)w*512 + ((cc ^ (w&3))<<3), &VB[buf][slot*8]);
    }
  };

  // prologue: Q->regs, K0, V0, K1; drain all but K1
  uint4 qreg[16];
  {
    const u16* qrow = qh + (size_t)(q0 + wv*16 + l15)*512;
    #pragma unroll
    for (int ks=0;ks<16;ks++) qreg[ks] = *(const uint4*)(qrow + ks*32 + l4*8);
  }
  stageK(0, 0); stageV(0, 0); stageK(1, 1);
  asm volatile("s_waitcnt vmcnt(4)" ::: "memory");
  __builtin_amdgcn_s_barrier(); memfence();

  f32x4 oacc[32];
  #pragma unroll
  for (int n=0;n<32;n++) oacc[n] = (f32x4){0.f,0.f,0.f,0.f};
  float m_run[4] = {-1e30f,-1e30f,-1e30f,-1e30f};
  float l_run[4] = {0.f,0.f,0.f,0.f};

  // per-lane LDS element bases; all loop offsets are compile-time immediates
  const int kbase = l15*512 + ((l4 ^ (l15&3))<<3);   // + n*8192 + ks*32
  const int vbase = l15*32  + ((l4 ^ (l15&3))<<3);   // + n*512
  const int pbase = (wv*16 + l15)*40;                // + l4*8
  const int prow  = (wv*16 + l4*4)*40;               // + r*40 + n*16 + l15

  for (int jt=0; jt<16; ++jt){
    int cur = jt & 1;
    const u16* Kc = &KB[cur][0];
    const u16* Vc = &VB[cur][0];

    // ===== S phase (issue V(jt+1) first so it flies under MFMA) =====
    if (jt < 15) stageV(jt+1, cur^1);

    f32x4 sA[2], sB[2];
    #pragma unroll
    for (int n=0;n<2;n++){ sA[n]=(f32x4){0,0,0,0}; sB[n]=(f32x4){0,0,0,0}; }
    __builtin_amdgcn_s_setprio(1);
    #pragma unroll
    for (int ks=0; ks<8; ++ks){
      B8 a; a.q = qreg[ks];
      #pragma unroll
      for (int n=0;n<2;n++){
        B8 bb; bb.q = *(const uint4*)(Kc + kbase + n*8192 + ks*32);
        sA[n] = MFMA16(a.v, bb.v, sA[n]);
      }
    }
    #pragma unroll
    for (int ks=8; ks<16; ++ks){
      B8 a; a.q = qreg[ks];
      #pragma unroll
      for (int n=0;n<2;n++){
        B8 bb; bb.q = *(const uint4*)(Kc + kbase + n*8192 + ks*32);
        sB[n] = MFMA16(a.v, bb.v, sB[n]);
      }
    }
    __builtin_amdgcn_s_setprio(0);
    f32x4 sacc0 = sA[0] + sB[0];
    f32x4 sacc1 = sA[1] + sB[1];

    // ===== wave-private online softmax (rows wv*16 + l4*4 + r), defer-max =====
    float pm[4], fc[4];
    bool need = false;
    #pragma unroll
    for (int r=0;r<4;r++){
      float p = fmaxf(sacc0[r], sacc1[r]);
      #pragma unroll
      for (int d=1; d<16; d<<=1) p = fmaxf(p, __shfl_xor(p, d, 64));
      pm[r] = p;
      need = need || (p > m_run[r] + 4.0f);
    }
    if (__any(need ? 1 : 0)){
      #pragma unroll
      for (int r=0;r<4;r++){
        float mn = fmaxf(m_run[r], pm[r]);
        fc[r] = exp2f(m_run[r] - mn);
        m_run[r] = mn;
      }
      #pragma unroll
      for (int n=0;n<32;n++)
        #pragma unroll
        for (int r=0;r<4;r++) oacc[n][r] *= fc[r];
    } else {
      fc[0]=fc[1]=fc[2]=fc[3]=1.0f;
    }
    #pragma unroll
    for (int r=0;r<4;r++){
      float e0 = exp2f(sacc0[r] - m_run[r]);
      float e1 = exp2f(sacc1[r] - m_run[r]);
      float s = e0 + e1;
      #pragma unroll
      for (int d=1; d<16; d<<=1) s += __shfl_xor(s, d, 64);
      l_run[r] = l_run[r]*fc[r] + s;
      sacc0[r] = e0; sacc1[r] = e1;
    }
    #pragma unroll
    for (int r=0;r<4;r++){
      Pt[prow + r*40 + l15]      = f2bf(sacc0[r]);
      Pt[prow + r*40 + 16 + l15] = f2bf(sacc1[r]);
    }

    // mid barrier: all waves done reading KB[cur] -> free for K(jt+2)
    asm volatile("s_waitcnt lgkmcnt(0)" ::: "memory");
    __builtin_amdgcn_s_barrier(); memfence();

    if (jt < 14) stageK(jt+2, cur);

    // ===== PV phase: O[own 16 q][512 w] += P(16x32) * V(32x512) =====
    B8 pa; pa.q = *(const uint4*)(Pt + pbase + l4*8);
    __builtin_amdgcn_s_setprio(1);
    #pragma unroll
    for (int n=0;n<32;n++){
      B8 bb; bb.q = *(const uint4*)(Vc + vbase + n*512);
      oacc[n] = MFMA16(pa.v, bb.v, oacc[n]);
    }
    __builtin_amdgcn_s_setprio(0);

    // end barrier: VB[cur] free; K(jt+1) landed (keep only newest stage in flight)
    if (jt < 15){
      asm volatile("s_waitcnt lgkmcnt(0)" ::: "memory");
      if (jt < 14) { asm volatile("s_waitcnt vmcnt(4)" ::: "memory"); }
      else         { asm volatile("s_waitcnt vmcnt(0)" ::: "memory"); }
      __builtin_amdgcn_s_barrier(); memfence();
    }
  }

  // ===== epilogue: write O interleaved-pair layout into o2 (for k4 staging) =====
  u16* dst = o2 + (size_t)b*33554432 + 16777216
                + (size_t)(c>>1)*524288 + (c&1);
  #pragma unroll
  for (int r=0;r<4;r++){
    float inv = 1.0f / l_run[r];
    int qq = q0 + wv*16 + l4*4 + r;
    #pragma unroll
    for (int n=0;n<32;n++){
      int w = n*16 + l15;
      dst[(size_t)qq*1024 + w*2] = f2bf(oacc[n][r]*inv);
    }
  }
}

// ---------------- K4 v2: out conv + BN + residual ----------------
__global__ __launch_bounds__(512,2)
void k4_out(const u16* __restrict__ o2, const u16* __restrict__ wz,
            const float* __restrict__ dz, const float* __restrict__ f,
            float* __restrict__ out)
{
  int bid = blockIdx.x;
  int b = bid >> 9;
  int h = bid & 511;
  int tid = threadIdx.x, wv = tid>>6, lane = tid&63;
  int l15 = lane&15, l4 = lane>>4;

  __shared__ u16 Ost[32*1032];

  const u16* src0 = o2 + (size_t)b*33554432 + 16777216 + (size_t)h*1024;
  #pragma unroll
  for (int jj=0;jj<4;jj++){
    int row = jj*8 + wv;
    const u16* srow = src0 + (size_t)row*524288;
    #pragma unroll
    for (int hf=0;hf<2;hf++){
      gld16(srow + hf*512 + lane*8, &Ost[row*1032 + hf*512 + lane*8]);
    }
  }

  bf16x8 wa[4][2];
  #pragma unroll
  for (int m=0;m<4;m++)
    #pragma unroll
    for (int ks=0;ks<2;ks++){
      B8 t; t.q = *(const uint4*)(wz + 3*4096 + (m*16+l15)*64 + ks*32 + l4*8);
      wa[m][ks] = t.v;
    }
  f32x4 dvv[4];
  #pragma unroll
  for (int m=0;m<4;m++) dvv[m] = *(const f32x4*)(dz + 3*64 + m*16 + l4*4);

  asm volatile("s_waitcnt vmcnt(0)" ::: "memory");
  __syncthreads();

  f32x4 acc[4][4];
  #pragma unroll
  for (int m=0;m<4;m++)
    #pragma unroll
    for (int n=0;n<4;n++) acc[m][n] = (f32x4){0.f,0.f,0.f,0.f};

  const u16* obase = Ost + l4*4128 + wv*128 + l15*2;
  #pragma unroll
  for (int ks=0;ks<2;ks++){
    #pragma unroll
    for (int n=0;n<4;n++){
      B8 bb;
      #pragma unroll
      for (int jj=0;jj<4;jj++)
        bb.u[jj] = *(const u32*)(obase + ks*16512 + jj*1032 + n*32);
      #pragma unroll
      for (int m=0;m<4;m++)
        acc[m][n] = MFMA16(wa[m][ks], bb.v, acc[m][n]);
    }
  }
  #pragma unroll
  for (int m=0;m<4;m++)
    #pragma unroll
    for (int n=0;n<4;n++)
      #pragma unroll
      for (int r=0;r<4;r++){
        int o = m*16 + l4*4 + r;
        int w = wv*64 + n*16 + l15;
        size_t idx = ((size_t)(b*64+o)*512 + h)*512 + w;
        out[idx] = acc[m][n][r] + dvv[m][r] + f[idx];
      }
}

// ---------------- launch ----------------
extern "C" void kernel_launch(void* const* d_in, const int* in_sizes, int n_in,
                              void* d_out, int out_size, void* d_ws, size_t ws_size,
                              hipStream_t stream) {
  const float* feat = (const float*)d_in[0];
  char* ws = (char*)d_ws;
  u16*   wz   = (u16*)ws;
  float* dz   = (float*)(ws + 32768);
  u16* bufQ = (u16*)(ws + 65536);     // q
  u16* bufK = bufQ + 67108864ull;     // k
  u16* bufV = bufK + 67108864ull;     // vT
  u16* o2   = (u16*)d_out;            // O pair-layout scratch in d_out's per-b upper 32MB

  float extraK = 1.4426950408889634f / sqrtf(512.0f);  // fold 1/sqrt(W)*log2(e) into K
  for (int m=0; m<4; m++){
    int base = 1 + m*6;
    float extra = (m==1) ? extraK : 1.0f;
    k0_prep<<<dim3(1), dim3(256), 0, stream>>>(
        (const float*)d_in[base+0], (const float*)d_in[base+1],
        (const float*)d_in[base+2], (const float*)d_in[base+3],
        (const float*)d_in[base+4], (const float*)d_in[base+5],
        extra, wz + m*4096, dz + m*64);
  }
  k1_qkv   <<<dim3(512),  dim3(256), 0, stream>>>(feat, wz, dz, bufQ, bufK, bufV);
  k23_attn <<<dim3(1024), dim3(512), 0, stream>>>(bufQ, bufK, bufV, o2);
  k4_out   <<<dim3(2048), dim3(512), 0, stream>>>(o2, wz, dz, feat, (float*)d_out);
}

// Round 7
// 804.667 us; speedup vs baseline: 1.4902x; 1.0624x over previous
//
#include <hip/hip_runtime.h>
#include <math.h>

typedef unsigned short u16;
typedef unsigned int u32;
typedef __attribute__((ext_vector_type(8))) short bf16x8;
typedef __attribute__((ext_vector_type(4))) float f32x4;

#define MFMA16(a,b,c) __builtin_amdgcn_mfma_f32_16x16x32_bf16(a,b,c,0,0,0)

typedef __attribute__((address_space(1))) const unsigned int as1_u32;
typedef __attribute__((address_space(3))) unsigned int as3_u32;
__device__ __forceinline__ void gld16(const u16* g, u16* l){
  __builtin_amdgcn_global_load_lds((as1_u32*)g, (as3_u32*)l, 16, 0, 0);
}

__device__ __forceinline__ u16 f2bf(float x){
  union { float f; u32 u; } v; v.f = x;
  u32 u = v.u;
  return (u16)((u + 0x7fffu + ((u>>16)&1u)) >> 16);
}

__device__ __forceinline__ void memfence(){ asm volatile("" ::: "memory"); }

union B8 { bf16x8 v; u32 u[4]; uint4 q; };

// ---------------- K0: fold BN into bf16 weights ----------------
__global__ void k0_prep(const float* wm, const float* bias, const float* gamma,
                        const float* beta, const float* mean, const float* var,
                        float extra, u16* wdst, float* ddst)
{
  int t = threadIdx.x;
  if (t < 64){
    float a0 = gamma[t] * rsqrtf(var[t] + 1e-5f);
    ddst[t] = (beta[t] + (bias[t] - mean[t]) * a0) * extra;
  }
  for (int i = t; i < 4096; i += 256){
    int o = i >> 6;
    float a0 = gamma[o] * rsqrtf(var[o] + 1e-5f);
    wdst[i] = f2bf(wm[i] * a0 * extra);
  }
}

// ---------------- K1: QKV projection + BN; q,k row-major, v transposed ----------
__global__ __launch_bounds__(256,2)
void k1_qkv(const float* __restrict__ f, const u16* __restrict__ wz,
            const float* __restrict__ dz, u16* __restrict__ q,
            u16* __restrict__ kk_, u16* __restrict__ vt)
{
  int bid = blockIdx.x;
  int b  = bid >> 7;
  int ht = (bid >> 3) & 15;
  int wt = bid & 7;
  int tid = threadIdx.x;
  int wv = tid >> 6, lane = tid & 63;
  int l15 = lane & 15, l4 = lane >> 4;
  int h0 = ht * 32;
  int w0 = wt * 64 + wv * 16;

  bf16x8 wa[3][4][2];
  #pragma unroll
  for (int mt=0; mt<3; mt++)
    #pragma unroll
    for (int m=0;m<4;m++)
      #pragma unroll
      for (int ks=0;ks<2;ks++){
        B8 t; t.q = *(const uint4*)(wz + mt*4096 + (m*16+l15)*64 + ks*32 + l4*8);
        wa[mt][m][ks] = t.v;
      }
  f32x4 dv[3][4];
  #pragma unroll
  for (int mt=0;mt<3;mt++)
    #pragma unroll
    for (int m=0;m<4;m++)
      dv[mt][m] = *(const f32x4*)(dz + mt*64 + m*16 + l4*4);

  __shared__ u16 vstage[4][8704];
  u16* vs = vstage[wv];

  B8 bf[2];
  #pragma unroll
  for (int ks=0;ks<2;ks++)
    #pragma unroll
    for (int jj=0;jj<4;jj++){
      int c0 = ks*32 + l4*8 + jj*2;
      size_t i0 = ((size_t)(b*64 + c0)*512 + h0)*512 + w0 + l15;
      bf[ks].u[jj] = (u32)f2bf(f[i0]) | ((u32)f2bf(f[i0 + 262144]) << 16);
    }

  for (int hh=0; hh<32; hh++){
    int h = h0 + hh;
    B8 bfn[2];
    if (hh < 31){
      #pragma unroll
      for (int ks=0;ks<2;ks++)
        #pragma unroll
        for (int jj=0;jj<4;jj++){
          int c0 = ks*32 + l4*8 + jj*2;
          size_t i0 = ((size_t)(b*64 + c0)*512 + h + 1)*512 + w0 + l15;
          bfn[ks].u[jj] = (u32)f2bf(f[i0]) | ((u32)f2bf(f[i0 + 262144]) << 16);
        }
    }
    #pragma unroll
    for (int mt=0; mt<3; mt++){
      f32x4 acc[4];
      #pragma unroll
      for (int m=0;m<4;m++) acc[m] = (f32x4){0.f,0.f,0.f,0.f};
      #pragma unroll
      for (int m=0;m<4;m++)
        #pragma unroll
        for (int ks=0;ks<2;ks++)
          acc[m] = MFMA16(wa[mt][m][ks], bf[ks].v, acc[m]);
      #pragma unroll
      for (int m=0;m<4;m++)
        #pragma unroll
        for (int r=0;r<4;r++){
          float val = acc[m][r] + dv[mt][m][r];
          u16 bv = f2bf(val);
          int o = m*16 + l4*4 + r;
          if (mt==0)      q  [((size_t)(b*64+o)*512 + h)*512 + w0 + l15] = bv;
          else if (mt==1) kk_[((size_t)(b*64+o)*512 + h)*512 + w0 + l15] = bv;
          else            vs[o*136 + l15*8 + (hh&7)] = bv;
        }
    }
    bf[0] = bfn[0]; bf[1] = bfn[1];
    if ((hh&7)==7){
      __syncthreads();
      int hb = h - 7;
      #pragma unroll
      for (int r=0;r<16;r++){
        int o = r*4 + l4;
        uint4 d = *(const uint4*)(vs + o*136 + l15*8);
        *(uint4*)(vt + ((size_t)(b*64+o)*512 + (w0+l15))*512 + hb) = d;
      }
      __syncthreads();
    }
  }
}

// ---------------- K23 v6: flash attention, padded-row K LDS (conflict-free) ----
// grid 1024, 512 thr (8 waves). QBLK=128 (wave owns 16 q-rows end-to-end),
// KVBLK=32, 16 tiles. K rows padded to 520 u16 (1040B): read bank-group =
// (l15+l4+4ks)%8 uniform -> conflict-free; staging = 1 row/gld16-instr
// (wave-uniform base + lane*16, contiguous 1KB source). V linear (reads
// already conflict-free: group=(l15&1)*4+l4). 2 barriers/iter, counted vmcnt.
__global__ __launch_bounds__(512,2)
void k23_attn(const u16* __restrict__ q, const u16* __restrict__ kten,
              const u16* __restrict__ vt, u16* __restrict__ o2)
{
  int phys = blockIdx.x;
  int x = phys & 7, j = phys >> 3;
  int qt = j & 3, hh = j >> 2;
  int head = x*32 + hh;
  int q0 = qt*128;
  int b = head >> 6, c = head & 63;

  int tid = threadIdx.x;
  int wv = tid >> 6, lane = tid & 63;
  int l15 = lane & 15, l4 = lane >> 4;

  const u16* qh = q    + (size_t)head*262144;
  const u16* kh = kten + (size_t)head*262144;
  const u16* vh = vt   + (size_t)head*262144;   // vh[w*512+g] = V[g][w]

  __shared__ u16 KB[2][16640];  // [g 0..31][520] rows padded +8 elems (1040B)
  __shared__ u16 VB[2][16384];  // [w 0..511][4 chunks] linear
  __shared__ u16 Pt[5120];      // [q 0..127][40] wave-private rows

  auto stageK = [&](int jt, int buf){
    const u16* src = kh + (size_t)jt*16384;
    #pragma unroll
    for (int i=0;i<4;i++){
      int row = i*8 + wv;                       // wave-uniform per instruction
      gld16(src + (size_t)row*512 + lane*8, &KB[buf][row*520 + lane*8]);
    }
  };
  auto stageV = [&](int jt, int buf){
    const u16* src = vh + jt*32;
    #pragma unroll
    for (int i=0;i<4;i++){
      int slot = i*512 + tid;
      int w = slot >> 2, cc = slot & 3;
      gld16(src + (size_t)w*512 + cc*8, &VB[buf][slot*8]);
    }
  };

  // prologue: Q->regs, K0, V0, K1; drain all but K1
  uint4 qreg[16];
  {
    const u16* qrow = qh + (size_t)(q0 + wv*16 + l15)*512;
    #pragma unroll
    for (int ks=0;ks<16;ks++) qreg[ks] = *(const uint4*)(qrow + ks*32 + l4*8);
  }
  stageK(0, 0); stageV(0, 0); stageK(1, 1);
  asm volatile("s_waitcnt vmcnt(4)" ::: "memory");
  __builtin_amdgcn_s_barrier(); memfence();

  f32x4 oacc[32];
  #pragma unroll
  for (int n=0;n<32;n++) oacc[n] = (f32x4){0.f,0.f,0.f,0.f};
  float m_run[4] = {-1e30f,-1e30f,-1e30f,-1e30f};
  float l_run[4] = {0.f,0.f,0.f,0.f};

  // per-lane LDS element bases; all loop offsets are compile-time immediates
  const int kbase = l15*520 + l4*8;              // + n*8320 + ks*32
  const int vbase = l15*32  + l4*8;              // + n*512
  const int pbase = (wv*16 + l15)*40;            // + l4*8
  const int prow  = (wv*16 + l4*4)*40;           // + r*40 + n*16 + l15

  for (int jt=0; jt<16; ++jt){
    int cur = jt & 1;
    const u16* Kc = &KB[cur][0];
    const u16* Vc = &VB[cur][0];

    // ===== S phase (issue V(jt+1) first so it flies under MFMA) =====
    if (jt < 15) stageV(jt+1, cur^1);

    f32x4 sA[2], sB[2];
    #pragma unroll
    for (int n=0;n<2;n++){ sA[n]=(f32x4){0,0,0,0}; sB[n]=(f32x4){0,0,0,0}; }
    __builtin_amdgcn_s_setprio(1);
    #pragma unroll
    for (int ks=0; ks<8; ++ks){
      B8 a; a.q = qreg[ks];
      #pragma unroll
      for (int n=0;n<2;n++){
        B8 bb; bb.q = *(const uint4*)(Kc + kbase + n*8320 + ks*32);
        sA[n] = MFMA16(a.v, bb.v, sA[n]);
      }
    }
    #pragma unroll
    for (int ks=8; ks<16; ++ks){
      B8 a; a.q = qreg[ks];
      #pragma unroll
      for (int n=0;n<2;n++){
        B8 bb; bb.q = *(const uint4*)(Kc + kbase + n*8320 + ks*32);
        sB[n] = MFMA16(a.v, bb.v, sB[n]);
      }
    }
    __builtin_amdgcn_s_setprio(0);
    f32x4 sacc0 = sA[0] + sB[0];
    f32x4 sacc1 = sA[1] + sB[1];

    // ===== wave-private online softmax (rows wv*16 + l4*4 + r), defer-max =====
    float pm[4], fc[4];
    bool need = false;
    #pragma unroll
    for (int r=0;r<4;r++){
      float p = fmaxf(sacc0[r], sacc1[r]);
      #pragma unroll
      for (int d=1; d<16; d<<=1) p = fmaxf(p, __shfl_xor(p, d, 64));
      pm[r] = p;
      need = need || (p > m_run[r] + 4.0f);
    }
    if (__any(need ? 1 : 0)){
      #pragma unroll
      for (int r=0;r<4;r++){
        float mn = fmaxf(m_run[r], pm[r]);
        fc[r] = exp2f(m_run[r] - mn);
        m_run[r] = mn;
      }
      #pragma unroll
      for (int n=0;n<32;n++)
        #pragma unroll
        for (int r=0;r<4;r++) oacc[n][r] *= fc[r];
    } else {
      fc[0]=fc[1]=fc[2]=fc[3]=1.0f;
    }
    #pragma unroll
    for (int r=0;r<4;r++){
      float e0 = exp2f(sacc0[r] - m_run[r]);
      float e1 = exp2f(sacc1[r] - m_run[r]);
      float s = e0 + e1;
      #pragma unroll
      for (int d=1; d<16; d<<=1) s += __shfl_xor(s, d, 64);
      l_run[r] = l_run[r]*fc[r] + s;
      sacc0[r] = e0; sacc1[r] = e1;
    }
    #pragma unroll
    for (int r=0;r<4;r++){
      Pt[prow + r*40 + l15]      = f2bf(sacc0[r]);
      Pt[prow + r*40 + 16 + l15] = f2bf(sacc1[r]);
    }

    // mid barrier: all waves done reading KB[cur] -> free for K(jt+2)
    asm volatile("s_waitcnt lgkmcnt(0)" ::: "memory");
    __builtin_amdgcn_s_barrier(); memfence();

    if (jt < 14) stageK(jt+2, cur);

    // ===== PV phase: O[own 16 q][512 w] += P(16x32) * V(32x512) =====
    B8 pa; pa.q = *(const uint4*)(Pt + pbase + l4*8);
    __builtin_amdgcn_s_setprio(1);
    #pragma unroll
    for (int n=0;n<32;n++){
      B8 bb; bb.q = *(const uint4*)(Vc + vbase + n*512);
      oacc[n] = MFMA16(pa.v, bb.v, oacc[n]);
    }
    __builtin_amdgcn_s_setprio(0);

    // end barrier: VB[cur] free; K(jt+1) landed (keep only newest stage in flight)
    if (jt < 15){
      asm volatile("s_waitcnt lgkmcnt(0)" ::: "memory");
      if (jt < 14) { asm volatile("s_waitcnt vmcnt(4)" ::: "memory"); }
      else         { asm volatile("s_waitcnt vmcnt(0)" ::: "memory"); }
      __builtin_amdgcn_s_barrier(); memfence();
    }
  }

  // ===== epilogue: write O interleaved-pair layout into o2 (for k4 staging) =====
  u16* dst = o2 + (size_t)b*33554432 + 16777216
                + (size_t)(c>>1)*524288 + (c&1);
  #pragma unroll
  for (int r=0;r<4;r++){
    float inv = 1.0f / l_run[r];
    int qq = q0 + wv*16 + l4*4 + r;
    #pragma unroll
    for (int n=0;n<32;n++){
      int w = n*16 + l15;
      dst[(size_t)qq*1024 + w*2] = f2bf(oacc[n][r]*inv);
    }
  }
}

// ---------------- K4 v2: out conv + BN + residual ----------------
__global__ __launch_bounds__(512,2)
void k4_out(const u16* __restrict__ o2, const u16* __restrict__ wz,
            const float* __restrict__ dz, const float* __restrict__ f,
            float* __restrict__ out)
{
  int bid = blockIdx.x;
  int b = bid >> 9;
  int h = bid & 511;
  int tid = threadIdx.x, wv = tid>>6, lane = tid&63;
  int l15 = lane&15, l4 = lane>>4;

  __shared__ u16 Ost[32*1032];

  const u16* src0 = o2 + (size_t)b*33554432 + 16777216 + (size_t)h*1024;
  #pragma unroll
  for (int jj=0;jj<4;jj++){
    int row = jj*8 + wv;
    const u16* srow = src0 + (size_t)row*524288;
    #pragma unroll
    for (int hf=0;hf<2;hf++){
      gld16(srow + hf*512 + lane*8, &Ost[row*1032 + hf*512 + lane*8]);
    }
  }

  bf16x8 wa[4][2];
  #pragma unroll
  for (int m=0;m<4;m++)
    #pragma unroll
    for (int ks=0;ks<2;ks++){
      B8 t; t.q = *(const uint4*)(wz + 3*4096 + (m*16+l15)*64 + ks*32 + l4*8);
      wa[m][ks] = t.v;
    }
  f32x4 dvv[4];
  #pragma unroll
  for (int m=0;m<4;m++) dvv[m] = *(const f32x4*)(dz + 3*64 + m*16 + l4*4);

  asm volatile("s_waitcnt vmcnt(0)" ::: "memory");
  __syncthreads();

  f32x4 acc[4][4];
  #pragma unroll
  for (int m=0;m<4;m++)
    #pragma unroll
    for (int n=0;n<4;n++) acc[m][n] = (f32x4){0.f,0.f,0.f,0.f};

  const u16* obase = Ost + l4*4128 + wv*128 + l15*2;
  #pragma unroll
  for (int ks=0;ks<2;ks++){
    #pragma unroll
    for (int n=0;n<4;n++){
      B8 bb;
      #pragma unroll
      for (int jj=0;jj<4;jj++)
        bb.u[jj] = *(const u32*)(obase + ks*16512 + jj*1032 + n*32);
      #pragma unroll
      for (int m=0;m<4;m++)
        acc[m][n] = MFMA16(wa[m][ks], bb.v, acc[m][n]);
    }
  }
  #pragma unroll
  for (int m=0;m<4;m++)
    #pragma unroll
    for (int n=0;n<4;n++)
      #pragma unroll
      for (int r=0;r<4;r++){
        int o = m*16 + l4*4 + r;
        int w = wv*64 + n*16 + l15;
        size_t idx = ((size_t)(b*64+o)*512 + h)*512 + w;
        out[idx] = acc[m][n][r] + dvv[m][r] + f[idx];
      }
}

// ---------------- launch ----------------
extern "C" void kernel_launch(void* const* d_in, const int* in_sizes, int n_in,
                              void* d_out, int out_size, void* d_ws, size_t ws_size,
                              hipStream_t stream) {
  const float* feat = (const float*)d_in[0];
  char* ws = (char*)d_ws;
  u16*   wz   = (u16*)ws;
  float* dz   = (float*)(ws + 32768);
  u16* bufQ = (u16*)(ws + 65536);     // q
  u16* bufK = bufQ + 67108864ull;     // k
  u16* bufV = bufK + 67108864ull;     // vT
  u16* o2   = (u16*)d_out;            // O pair-layout scratch in d_out's per-b upper 32MB

  float extraK = 1.4426950408889634f / sqrtf(512.0f);  // fold 1/sqrt(W)*log2(e) into K
  for (int m=0; m<4; m++){
    int base = 1 + m*6;
    float extra = (m==1) ? extraK : 1.0f;
    k0_prep<<<dim3(1), dim3(256), 0, stream>>>(
        (const float*)d_in[base+0], (const float*)d_in[base+1],
        (const float*)d_in[base+2], (const float*)d_in[base+3],
        (const float*)d_in[base+4], (const float*)d_in[base+5],
        extra, wz + m*4096, dz + m*64);
  }
  k1_qkv   <<<dim3(512),  dim3(256), 0, stream>>>(feat, wz, dz, bufQ, bufK, bufV);
  k23_attn <<<dim3(1024), dim3(512), 0, stream>>>(bufQ, bufK, bufV, o2);
  k4_out   <<<dim3(2048), dim3(512), 0, stream>>>(o2, wz, dz, feat, (float*)d_out);
}